// Round 11
// baseline (555.348 us; speedup 1.0000x reference)
//
#include <hip/hip_runtime.h>
#include <hip/hip_bf16.h>
#include <math.h>

#define C128 128
#define OUT_CH 10
#define NSUB 16                 // sub-counters per partition (atomic decontention)
#define CAP 15360               // capacity per (sub,partition) bucket.
                                // Partition 0 holds 13984 nodes (2048-node chunks: 48 full
                                // + 1696 remainder -> p0), so worst bucket mean ~= 14000,
                                // sigma ~110 -> 15360 is >12 sigma. R10's 13056 overflowed.

typedef __attribute__((ext_vector_type(8))) short short8;
typedef __attribute__((ext_vector_type(8))) unsigned short ushort8v;
typedef __attribute__((ext_vector_type(4))) float f32x4;

__device__ __forceinline__ unsigned short f2bf(float f) {
    unsigned b = __float_as_uint(f);
    unsigned r = (b + 0x7FFF + ((b >> 16) & 1)) >> 16;   // RNE
    return (unsigned short)r;
}
__device__ __forceinline__ float bf2f(unsigned short u) {
    return __uint_as_float(((unsigned)u) << 16);
}

// ---------------- CSR build, two-pass ----------------
// Pass 1 (bin): stream edges ONCE; deg histogram + append records into
// 128 = 16sub x 8part buckets (append-only -> lines fill immediately, no
// long-window partial-line thrash). Record: (dst, (src<<15)|wq).
// Pass 2 (fill2): per-partition (XCD-aligned via blockIdx&7) scatter from the
// staged bucket into csr; the partition's csr+cursor slice (~0.9 MB) is
// L2-resident, so scatter lines fill completely and write back once.

__global__ __launch_bounds__(256) void bin_kernel(
    const int* __restrict__ ei, const float* __restrict__ ew,
    int* __restrict__ deg, int* __restrict__ pcnt,
    long long* __restrict__ staged, int E)
{
    __shared__ int lcnt[8];
    __shared__ int lbase[8];
    int t = threadIdx.x;
    if (t < 8) lcnt[t] = 0;
    __syncthreads();
    int e = blockIdx.x * 256 + t;
    int sub = blockIdx.x & (NSUB - 1);
    bool valid = e < E;
    int dst = 0, p = 0, myofs = 0;
    unsigned rec = 0;
    if (valid) {
        dst = ei[E + e];
        int src = __builtin_nontemporal_load(&ei[e]);
        float w = __builtin_nontemporal_load(&ew[e]);
        atomicAdd(&deg[dst], 1);
        p = (dst >> 11) & 7;
        int wq = (int)(w * 32768.0f);
        if (wq > 32767) wq = 32767;
        rec = ((unsigned)src << 15) | (unsigned)wq;
        myofs = atomicAdd(&lcnt[p], 1);
    }
    __syncthreads();
    if (t < 8) lbase[t] = atomicAdd(&pcnt[sub * 8 + t], lcnt[t]);
    __syncthreads();
    if (valid) {
        int pos = lbase[p] + myofs;
        if (pos < CAP) {
            long long v = ((long long)(int)rec << 32) | (unsigned)dst;
            __builtin_nontemporal_store(v, &staged[(size_t)(sub * 8 + p) * CAP + pos]);
        }
    }
}

__global__ __launch_bounds__(256) void fill2_kernel(
    const long long* __restrict__ staged, const int* __restrict__ pcnt,
    int* __restrict__ cursor, unsigned* __restrict__ csr, int chunksPerP)
{
    int p = blockIdx.x & 7;
    int chunk = blockIdx.x >> 3;
    for (int sub = 0; sub < NSUB; ++sub) {
        int cnt = pcnt[sub * 8 + p];
        if (cnt > CAP) cnt = CAP;
        const long long* base = staged + (size_t)(sub * 8 + p) * CAP;
        for (int i = chunk * 256 + threadIdx.x; i < cnt; i += chunksPerP * 256) {
            long long v = __builtin_nontemporal_load(&base[i]);
            int dst = (int)(v & 0xffffffffLL);
            unsigned rec = (unsigned)(v >> 32);
            int pos = atomicAdd(&cursor[dst], 1);
            csr[pos] = rec;
        }
    }
}

__global__ __launch_bounds__(256) void tile_sum_kernel(const int* __restrict__ deg,
                                                       int* __restrict__ tile_sums, int N) {
    __shared__ int red[256];
    int t = threadIdx.x;
    int i = blockIdx.x * 256 + t;
    red[t] = (i < N) ? deg[i] : 0;
    __syncthreads();
    for (int off = 128; off > 0; off >>= 1) {
        if (t < off) red[t] += red[t + off];
        __syncthreads();
    }
    if (t == 0) tile_sums[blockIdx.x] = red[0];
}

__global__ __launch_bounds__(512) void tile_scan_kernel(const int* __restrict__ tile_sums,
                                                        int* __restrict__ tile_off, int numTiles) {
    __shared__ int s[512];
    int t = threadIdx.x;
    int v = (t < numTiles) ? tile_sums[t] : 0;
    s[t] = v;
    __syncthreads();
    for (int off = 1; off < 512; off <<= 1) {
        int u = (t >= off) ? s[t - off] : 0;
        __syncthreads();
        s[t] += u;
        __syncthreads();
    }
    if (t < numTiles) tile_off[t] = s[t] - v;
}

__global__ __launch_bounds__(256) void scan_emit_kernel(int* __restrict__ deg_cursor,
                                                        const int* __restrict__ tile_off,
                                                        int* __restrict__ row_ptr, int N, int E) {
    __shared__ int s[256];
    int t = threadIdx.x;
    int i = blockIdx.x * 256 + t;
    int v = (i < N) ? deg_cursor[i] : 0;
    s[t] = v;
    __syncthreads();
    for (int off = 1; off < 256; off <<= 1) {
        int u = (t >= off) ? s[t - off] : 0;
        __syncthreads();
        s[t] += u;
        __syncthreads();
    }
    if (i < N) {
        int o = tile_off[blockIdx.x] + s[t] - v;
        row_ptr[i] = o;
        deg_cursor[i] = o;
    }
    if (blockIdx.x == 0 && t == 0) row_ptr[N] = E;
}

// ---------------- fp32 -> bf16 conversion (layer-1 input) ----------------

__global__ __launch_bounds__(256) void cvt_bf16_kernel(const float4* __restrict__ x,
                                                       ushort4* __restrict__ xb, int n4) {
    int i = blockIdx.x * blockDim.x + threadIdx.x;
    if (i < n4) {
        float4 v = x[i];
        ushort4 o;
        o.x = f2bf(v.x); o.y = f2bf(v.y); o.z = f2bf(v.z); o.w = f2bf(v.w);
        xb[i] = o;
    }
}

// ---------------- weight pack: [Wr;Wt] (256x128 fp32) -> MFMA B-frag order bf16 ----------------

__global__ __launch_bounds__(256) void pack_w_kernel(const float* __restrict__ Wr,
                                                     const float* __restrict__ Wt,
                                                     unsigned short* __restrict__ Wp) {
    int idx = blockIdx.x * 256 + threadIdx.x;     // 32768
    int j    = idx & 7;
    int n    = (idx >> 3) & 127;
    int quad = (idx >> 10) & 3;
    int ks   = idx >> 12;
    const float* W = (ks < 4) ? Wr : Wt;
    int k = (ks & 3) * 32 + quad * 8 + j;
    Wp[idx] = f2bf(W[(size_t)k * C128 + n]);
}

// ---------------- aggregation: wave-wide record broadcast, 4B records ----------------

__global__ __launch_bounds__(256) void gather_bf16_kernel(
    const unsigned short* __restrict__ xb, const int* __restrict__ row_ptr,
    const unsigned* __restrict__ csr, unsigned short* __restrict__ aggb, int N)
{
    int node = blockIdx.x * 4 + (threadIdx.x >> 6);
    if (node >= N) return;
    int lane = threadIdx.x & 63;
    int g   = lane >> 4;        // chunk slot 0..3
    int l16 = lane & 15;        // channel group (8 bf16 = 16 B)
    int i0  = row_ptr[node];
    int deg = row_ptr[node + 1] - i0;
    const float wscale = 1.0f / 32768.0f;

    float acc[8];
#pragma unroll
    for (int j = 0; j < 8; ++j) acc[j] = 0.f;

    for (int base = 0; base < deg; base += 64) {
        int rem = deg - base; if (rem > 64) rem = 64;
        unsigned rec = 0;
        if (base + lane < deg) rec = csr[i0 + base + lane];

        int c = 0;
        for (; c + 16 <= rem; c += 16) {
            unsigned r0 = (unsigned)__shfl((int)rec, c + g,      64);
            unsigned r1 = (unsigned)__shfl((int)rec, c + 4 + g,  64);
            unsigned r2 = (unsigned)__shfl((int)rec, c + 8 + g,  64);
            unsigned r3 = (unsigned)__shfl((int)rec, c + 12 + g, 64);
            ushort8v raw0 = *(const ushort8v*)&xb[(size_t)(r0 >> 15) * C128 + l16 * 8];
            ushort8v raw1 = *(const ushort8v*)&xb[(size_t)(r1 >> 15) * C128 + l16 * 8];
            ushort8v raw2 = *(const ushort8v*)&xb[(size_t)(r2 >> 15) * C128 + l16 * 8];
            ushort8v raw3 = *(const ushort8v*)&xb[(size_t)(r3 >> 15) * C128 + l16 * 8];
            float w0 = (float)(r0 & 0x7fffu) * wscale;
            float w1 = (float)(r1 & 0x7fffu) * wscale;
            float w2 = (float)(r2 & 0x7fffu) * wscale;
            float w3 = (float)(r3 & 0x7fffu) * wscale;
#pragma unroll
            for (int j = 0; j < 8; ++j) acc[j] += bf2f(raw0[j]) * w0;
#pragma unroll
            for (int j = 0; j < 8; ++j) acc[j] += bf2f(raw1[j]) * w1;
#pragma unroll
            for (int j = 0; j < 8; ++j) acc[j] += bf2f(raw2[j]) * w2;
#pragma unroll
            for (int j = 0; j < 8; ++j) acc[j] += bf2f(raw3[j]) * w3;
        }
        for (; c < rem; c += 4) {
            int idx = c + g;
            unsigned r = (unsigned)__shfl((int)rec, idx & 63, 64);
            float w = (float)(r & 0x7fffu) * wscale;
            if (idx >= rem) w = 0.f;
            ushort8v raw = *(const ushort8v*)&xb[(size_t)(r >> 15) * C128 + l16 * 8];
#pragma unroll
            for (int j = 0; j < 8; ++j) acc[j] += bf2f(raw[j]) * w;
        }
    }

#pragma unroll
    for (int j = 0; j < 8; ++j) {
        acc[j] += __shfl_xor(acc[j], 16, 64);
        acc[j] += __shfl_xor(acc[j], 32, 64);
    }
    if (g == 0) {
        uint4 o;
        o.x = (unsigned)f2bf(acc[0]) | ((unsigned)f2bf(acc[1]) << 16);
        o.y = (unsigned)f2bf(acc[2]) | ((unsigned)f2bf(acc[3]) << 16);
        o.z = (unsigned)f2bf(acc[4]) | ((unsigned)f2bf(acc[5]) << 16);
        o.w = (unsigned)f2bf(acc[6]) | ((unsigned)f2bf(acc[7]) << 16);
        *(uint4*)&aggb[(size_t)node * C128 + l16 * 8] = o;
    }
}

// ---------------- MFMA dual GEMM: out = relu([aggb|xb] @ [Wr;Wt] + b), bf16 out ----------------

#define A_STRIDE 40   // bf16 elements per staged row (32 data + 8 pad)

__global__ __launch_bounds__(256) void gemm_mfma(
    const unsigned short* __restrict__ aggb, const unsigned short* __restrict__ xb,
    const unsigned short* __restrict__ Wp, const float* __restrict__ bias,
    unsigned short* __restrict__ outb, int N)
{
    __shared__ unsigned short WL[8 * 4 * 128 * 8];   // 64 KB, full packed weights
    __shared__ unsigned short AL[64 * A_STRIDE];     // 5 KB, one 64x32 A chunk

    const int t = threadIdx.x;
    const int node0 = blockIdx.x * 64;
    const int w    = t >> 6;
    const int lane = t & 63;
    const int l15  = lane & 15;
    const int quad = lane >> 4;

#pragma unroll
    for (int i = 0; i < 16; ++i) {
        int slot = i * 256 + t;
        *(uint4*)&WL[slot * 8] = *(const uint4*)&Wp[slot * 8];
    }

    float bv[8];
#pragma unroll
    for (int nt = 0; nt < 8; ++nt) bv[nt] = bias[nt * 16 + l15];

    f32x4 acc[8];
#pragma unroll
    for (int nt = 0; nt < 8; ++nt) acc[nt] = (f32x4){0.f, 0.f, 0.f, 0.f};

    const int sr = t >> 2;        // 0..63
    const int sc = t & 3;         // 0..3
    const int srow = node0 + sr;

    for (int ks = 0; ks < 8; ++ks) {
        const unsigned short* Asrc = (ks < 4) ? aggb : xb;
        const int koff = (ks & 3) * 32;
        __syncthreads();
        uint4 av = make_uint4(0u, 0u, 0u, 0u);
        if (srow < N) av = *(const uint4*)&Asrc[(size_t)srow * C128 + koff + sc * 8];
        *(uint4*)&AL[sr * A_STRIDE + sc * 8] = av;
        __syncthreads();

        short8 a = *(const short8*)&AL[(w * 16 + l15) * A_STRIDE + quad * 8];
#pragma unroll
        for (int nt = 0; nt < 8; ++nt) {
            short8 b = *(const short8*)&WL[(((ks * 4 + quad) * 128) + nt * 16 + l15) * 8];
            acc[nt] = __builtin_amdgcn_mfma_f32_16x16x32_bf16(a, b, acc[nt], 0, 0, 0);
        }
    }

#pragma unroll
    for (int r = 0; r < 4; ++r) {
        int row = node0 + w * 16 + quad * 4 + r;
        if (row < N) {
#pragma unroll
            for (int nt = 0; nt < 8; ++nt) {
                float v = fmaxf(acc[nt][r] + bv[nt], 0.f);
                outb[(size_t)row * C128 + nt * 16 + l15] = f2bf(v);
            }
        }
    }
}

// ---------------- head: bf16 x3 @ W_lin + b_lin, log_softmax ----------------

__global__ __launch_bounds__(256) void head_kernel(
    const unsigned short* __restrict__ x, const float* __restrict__ Wl,
    const float* __restrict__ bl, float* __restrict__ out, int N)
{
    int n = blockIdx.x * blockDim.x + threadIdx.x;
    if (n >= N) return;
    float acc[OUT_CH];
#pragma unroll
    for (int c = 0; c < OUT_CH; ++c) acc[c] = bl[c];
    const ushort4* row = (const ushort4*)(x + (size_t)n * C128);
#pragma unroll 4
    for (int kk = 0; kk < 32; ++kk) {
        ushort4 u = row[kk];
        float vx = bf2f(u.x), vy = bf2f(u.y), vz = bf2f(u.z), vw = bf2f(u.w);
        int k = kk * 4;
#pragma unroll
        for (int c = 0; c < OUT_CH; ++c) {
            acc[c] += vx * Wl[(k + 0) * OUT_CH + c]
                    + vy * Wl[(k + 1) * OUT_CH + c]
                    + vz * Wl[(k + 2) * OUT_CH + c]
                    + vw * Wl[(k + 3) * OUT_CH + c];
        }
    }
    float m = acc[0];
#pragma unroll
    for (int c = 1; c < OUT_CH; ++c) m = fmaxf(m, acc[c]);
    float s = 0.f;
#pragma unroll
    for (int c = 0; c < OUT_CH; ++c) s += __expf(acc[c] - m);
    float lse = m + __logf(s);
#pragma unroll
    for (int c = 0; c < OUT_CH; ++c) out[(size_t)n * OUT_CH + c] = acc[c] - lse;
}

// ---------------- launch ----------------

extern "C" void kernel_launch(void* const* d_in, const int* in_sizes, int n_in,
                              void* d_out, int out_size, void* d_ws, size_t ws_size,
                              hipStream_t stream) {
    const float* x0   = (const float*)d_in[0];
    const int*   ei   = (const int*)  d_in[1];
    const float* ew   = (const float*)d_in[2];
    const float* W1r  = (const float*)d_in[3];
    const float* b1   = (const float*)d_in[4];
    const float* W1t  = (const float*)d_in[5];
    const float* W2r  = (const float*)d_in[6];
    const float* b2   = (const float*)d_in[7];
    const float* W2t  = (const float*)d_in[8];
    const float* W3r  = (const float*)d_in[9];
    const float* b3   = (const float*)d_in[10];
    const float* W3t  = (const float*)d_in[11];
    const float* Wlin = (const float*)d_in[12];
    const float* blin = (const float*)d_in[13];

    const int N = in_sizes[0] / C128;
    const int E = in_sizes[1] / 2;
    const int numTiles = (N + 255) / 256;

    char* ws = (char*)d_ws;
    size_t bb = (size_t)N * C128 * sizeof(unsigned short);   // 25.6 MB
    unsigned short* aggb = (unsigned short*)(ws);
    unsigned short* xb0  = (unsigned short*)(ws + bb);
    unsigned short* xb1  = (unsigned short*)(ws + 2 * bb);
    unsigned short* Wp1  = (unsigned short*)(ws + 3 * bb);   // 3 x 32768 ushorts
    unsigned short* Wp2  = Wp1 + 32768;
    unsigned short* Wp3  = Wp2 + 32768;
    unsigned*  csr     = (unsigned*)(ws + 3 * bb + 3 * 32768 * sizeof(unsigned short));
    long long* staged  = (long long*)(csr + E);              // 128 x CAP x 8B ~ 15.7 MB
    int* row_ptr   = (int*)(staged + (size_t)NSUB * 8 * CAP);
    int* cursor    = row_ptr + (N + 1);       // deg histogram, then fill cursor
    int* pcnt      = cursor + N;              // 128 bucket counters (zeroed with cursor)
    int* tile_sums = pcnt + NSUB * 8;
    int* tile_off  = tile_sums + 512;

    const int edgeBlocks = (E + 255) / 256;
    const int chunksPerP = 256;

    // build CSR (dst-indexed), once per call — two-pass binned
    hipMemsetAsync(cursor, 0, (size_t)(N + NSUB * 8) * sizeof(int), stream);
    bin_kernel<<<edgeBlocks, 256, 0, stream>>>(ei, ew, cursor, pcnt, staged, E);
    tile_sum_kernel<<<numTiles, 256, 0, stream>>>(cursor, tile_sums, N);
    tile_scan_kernel<<<1, 512, 0, stream>>>(tile_sums, tile_off, numTiles);
    scan_emit_kernel<<<numTiles, 256, 0, stream>>>(cursor, tile_off, row_ptr, N, E);
    fill2_kernel<<<chunksPerP * 8, 256, 0, stream>>>(staged, pcnt, cursor, csr, chunksPerP);

    // bf16 input + packed weights
    cvt_bf16_kernel<<<(N * C128 / 4 + 255) / 256, 256, 0, stream>>>(
        (const float4*)x0, (ushort4*)xb0, N * C128 / 4);
    pack_w_kernel<<<128, 256, 0, stream>>>(W1r, W1t, Wp1);
    pack_w_kernel<<<128, 256, 0, stream>>>(W2r, W2t, Wp2);
    pack_w_kernel<<<128, 256, 0, stream>>>(W3r, W3t, Wp3);

    int gatherGrid = (N + 3) / 4;
    int gemmGrid   = (N + 63) / 64;

    // layer 1
    gather_bf16_kernel<<<gatherGrid, 256, 0, stream>>>(xb0, row_ptr, csr, aggb, N);
    gemm_mfma<<<gemmGrid, 256, 0, stream>>>(aggb, xb0, Wp1, b1, xb1, N);
    // layer 2
    gather_bf16_kernel<<<gatherGrid, 256, 0, stream>>>(xb1, row_ptr, csr, aggb, N);
    gemm_mfma<<<gemmGrid, 256, 0, stream>>>(aggb, xb1, Wp2, b2, xb0, N);
    // layer 3
    gather_bf16_kernel<<<gatherGrid, 256, 0, stream>>>(xb0, row_ptr, csr, aggb, N);
    gemm_mfma<<<gemmGrid, 256, 0, stream>>>(aggb, xb0, Wp3, b3, xb1, N);
    // head
    head_kernel<<<(N + 255) / 256, 256, 0, stream>>>(xb1, Wlin, blin, (float*)d_out, N);
}

// Round 12
// 528.858 us; speedup vs baseline: 1.0501x; 1.0501x over previous
//
#include <hip/hip_runtime.h>
#include <hip/hip_bf16.h>
#include <math.h>

#define C128 128
#define OUT_CH 10

typedef __attribute__((ext_vector_type(8))) short short8;
typedef __attribute__((ext_vector_type(4))) float f32x4;
typedef __attribute__((ext_vector_type(2))) float f32x2;

__device__ __forceinline__ unsigned short f2bf(float f) {
    unsigned b = __float_as_uint(f);
    unsigned r = (b + 0x7FFF + ((b >> 16) & 1)) >> 16;   // RNE
    return (unsigned short)r;
}
__device__ __forceinline__ float bf2f(unsigned short u) {
    return __uint_as_float(((unsigned)u) << 16);
}

// ---------------- CSR build (R8 structure — measured best) ----------------
// XCD partitioning: blocks round-robin across XCDs; block with (blockIdx&7)==p
// only touches dsts with ((dst>>11)&7)==p. NT on streams; csr/cursor cached.

__global__ void hist_kernel(const int* __restrict__ ei, int* __restrict__ deg, int E) {
    int p = blockIdx.x & 7;
    int e = (blockIdx.x >> 3) * blockDim.x + threadIdx.x;
    if (e < E) {
        int dst = __builtin_nontemporal_load(&ei[E + e]);
        if (((dst >> 11) & 7) == p) atomicAdd(&deg[dst], 1);
    }
}

__global__ __launch_bounds__(256) void tile_sum_kernel(const int* __restrict__ deg,
                                                       int* __restrict__ tile_sums, int N) {
    __shared__ int red[256];
    int t = threadIdx.x;
    int i = blockIdx.x * 256 + t;
    red[t] = (i < N) ? deg[i] : 0;
    __syncthreads();
    for (int off = 128; off > 0; off >>= 1) {
        if (t < off) red[t] += red[t + off];
        __syncthreads();
    }
    if (t == 0) tile_sums[blockIdx.x] = red[0];
}

__global__ __launch_bounds__(512) void tile_scan_kernel(const int* __restrict__ tile_sums,
                                                        int* __restrict__ tile_off, int numTiles) {
    __shared__ int s[512];
    int t = threadIdx.x;
    int v = (t < numTiles) ? tile_sums[t] : 0;
    s[t] = v;
    __syncthreads();
    for (int off = 1; off < 512; off <<= 1) {
        int u = (t >= off) ? s[t - off] : 0;
        __syncthreads();
        s[t] += u;
        __syncthreads();
    }
    if (t < numTiles) tile_off[t] = s[t] - v;
}

__global__ __launch_bounds__(256) void scan_emit_kernel(int* __restrict__ deg_cursor,
                                                        const int* __restrict__ tile_off,
                                                        int* __restrict__ row_ptr, int N, int E) {
    __shared__ int s[256];
    int t = threadIdx.x;
    int i = blockIdx.x * 256 + t;
    int v = (i < N) ? deg_cursor[i] : 0;
    s[t] = v;
    __syncthreads();
    for (int off = 1; off < 256; off <<= 1) {
        int u = (t >= off) ? s[t - off] : 0;
        __syncthreads();
        s[t] += u;
        __syncthreads();
    }
    if (i < N) {
        int o = tile_off[blockIdx.x] + s[t] - v;
        row_ptr[i] = o;
        deg_cursor[i] = o;
    }
    if (blockIdx.x == 0 && t == 0) row_ptr[N] = E;
}

__global__ void fill_kernel(const int* __restrict__ ei, const float* __restrict__ ew,
                            int* __restrict__ cursor, int2* __restrict__ csr, int E) {
    int p = blockIdx.x & 7;
    int e = (blockIdx.x >> 3) * blockDim.x + threadIdx.x;
    if (e < E) {
        int dst = __builtin_nontemporal_load(&ei[E + e]);
        if (((dst >> 11) & 7) == p) {
            int src = __builtin_nontemporal_load(&ei[e]);
            float w = __builtin_nontemporal_load(&ew[e]);
            int pos = atomicAdd(&cursor[dst], 1);
            csr[pos] = make_int2(src, __float_as_int(w));
        }
    }
}

// ---------------- conversions (layer-1 input) ----------------

__global__ __launch_bounds__(256) void cvt_bf16_kernel(const float4* __restrict__ x,
                                                       ushort4* __restrict__ xb, int n4) {
    int i = blockIdx.x * blockDim.x + threadIdx.x;
    if (i < n4) {
        float4 v = x[i];
        ushort4 o;
        o.x = f2bf(v.x); o.y = f2bf(v.y); o.z = f2bf(v.z); o.w = f2bf(v.w);
        xb[i] = o;
    }
}

__global__ __launch_bounds__(256) void cvt_fp8_kernel(const float4* __restrict__ x,
                                                      unsigned* __restrict__ xf8, int n4) {
    int i = blockIdx.x * blockDim.x + threadIdx.x;
    if (i < n4) {
        float4 v = x[i];
        unsigned p = __builtin_amdgcn_cvt_pk_fp8_f32(v.x, v.y, 0, false);
        p = __builtin_amdgcn_cvt_pk_fp8_f32(v.z, v.w, p, true);
        xf8[i] = p;
    }
}

// ---------------- weight pack: [Wr;Wt] (256x128 fp32) -> MFMA B-frag order bf16 ----------------

__global__ __launch_bounds__(256) void pack_w_kernel(const float* __restrict__ Wr,
                                                     const float* __restrict__ Wt,
                                                     unsigned short* __restrict__ Wp) {
    int idx = blockIdx.x * 256 + threadIdx.x;     // 32768
    int j    = idx & 7;
    int n    = (idx >> 3) & 127;
    int quad = (idx >> 10) & 3;
    int ks   = idx >> 12;
    const float* W = (ks < 4) ? Wr : Wt;
    int k = (ks & 3) * 32 + quad * 8 + j;
    Wp[idx] = f2bf(W[(size_t)k * C128 + n]);
}

// ---------------- aggregation: wave-wide record broadcast, fp8 row reads ----------------
// One wave per node; lane l loads record csr[i0+l] (coalesced), records fan out
// via __shfl. Row slice per edge: 16 lanes x 8 B fp8 = 128 B. Dequant via
// v_cvt_pk_f32_fp8; fp32 accumulate; bf16 agg out.

__global__ __launch_bounds__(256) void gather_fp8_kernel(
    const unsigned* __restrict__ xf8,   // [N][32] words = 128 fp8 ch/row
    const int* __restrict__ row_ptr,
    const long long* __restrict__ csr, unsigned short* __restrict__ aggb, int N)
{
    int node = blockIdx.x * 4 + (threadIdx.x >> 6);
    if (node >= N) return;
    int lane = threadIdx.x & 63;
    int g   = lane >> 4;        // chunk slot 0..3
    int l16 = lane & 15;        // channel group (8 fp8 = 8 B = 2 words)
    int i0  = row_ptr[node];
    int deg = row_ptr[node + 1] - i0;

    float acc[8];
#pragma unroll
    for (int j = 0; j < 8; ++j) acc[j] = 0.f;

    for (int base = 0; base < deg; base += 64) {
        int rem = deg - base; if (rem > 64) rem = 64;
        long long rec = 0;
        if (base + lane < deg) rec = csr[i0 + base + lane];
        int rlo = (int)(rec & 0xffffffffLL);
        int rhi = (int)(rec >> 32);

        int c = 0;
        for (; c + 16 <= rem; c += 16) {
            int s0 = __shfl(rlo, c + g,      64);
            int s1 = __shfl(rlo, c + 4 + g,  64);
            int s2 = __shfl(rlo, c + 8 + g,  64);
            int s3 = __shfl(rlo, c + 12 + g, 64);
            float w0 = __uint_as_float((unsigned)__shfl(rhi, c + g,      64));
            float w1 = __uint_as_float((unsigned)__shfl(rhi, c + 4 + g,  64));
            float w2 = __uint_as_float((unsigned)__shfl(rhi, c + 8 + g,  64));
            float w3 = __uint_as_float((unsigned)__shfl(rhi, c + 12 + g, 64));
            uint2 q0 = *(const uint2*)&xf8[(size_t)s0 * 32 + l16 * 2];
            uint2 q1 = *(const uint2*)&xf8[(size_t)s1 * 32 + l16 * 2];
            uint2 q2 = *(const uint2*)&xf8[(size_t)s2 * 32 + l16 * 2];
            uint2 q3 = *(const uint2*)&xf8[(size_t)s3 * 32 + l16 * 2];
#define ACCUM(q, w)                                                          \
            {                                                                \
                f32x2 a01 = __builtin_amdgcn_cvt_pk_f32_fp8((q).x, false);   \
                f32x2 a23 = __builtin_amdgcn_cvt_pk_f32_fp8((q).x, true);    \
                f32x2 a45 = __builtin_amdgcn_cvt_pk_f32_fp8((q).y, false);   \
                f32x2 a67 = __builtin_amdgcn_cvt_pk_f32_fp8((q).y, true);    \
                acc[0] += a01.x * (w); acc[1] += a01.y * (w);                \
                acc[2] += a23.x * (w); acc[3] += a23.y * (w);                \
                acc[4] += a45.x * (w); acc[5] += a45.y * (w);                \
                acc[6] += a67.x * (w); acc[7] += a67.y * (w);                \
            }
            ACCUM(q0, w0) ACCUM(q1, w1) ACCUM(q2, w2) ACCUM(q3, w3)
        }
        for (; c < rem; c += 4) {
            int idx = c + g;
            int im = idx & 63;
            int s = __shfl(rlo, im, 64);
            float w = __uint_as_float((unsigned)__shfl(rhi, im, 64));
            if (idx >= rem) w = 0.f;
            uint2 q = *(const uint2*)&xf8[(size_t)s * 32 + l16 * 2];
            ACCUM(q, w)
        }
#undef ACCUM
    }

#pragma unroll
    for (int j = 0; j < 8; ++j) {
        acc[j] += __shfl_xor(acc[j], 16, 64);
        acc[j] += __shfl_xor(acc[j], 32, 64);
    }
    if (g == 0) {
        uint4 o;
        o.x = (unsigned)f2bf(acc[0]) | ((unsigned)f2bf(acc[1]) << 16);
        o.y = (unsigned)f2bf(acc[2]) | ((unsigned)f2bf(acc[3]) << 16);
        o.z = (unsigned)f2bf(acc[4]) | ((unsigned)f2bf(acc[5]) << 16);
        o.w = (unsigned)f2bf(acc[6]) | ((unsigned)f2bf(acc[7]) << 16);
        *(uint4*)&aggb[(size_t)node * C128 + l16 * 8] = o;
    }
}

// ---------------- MFMA dual GEMM: out = relu([aggb|xb] @ [Wr;Wt] + b) ----------------
// bf16 out always; optional fp8 copy (for next layer's gather).

#define A_STRIDE 40   // bf16 elements per staged row (32 data + 8 pad)

__global__ __launch_bounds__(256) void gemm_mfma(
    const unsigned short* __restrict__ aggb, const unsigned short* __restrict__ xb,
    const unsigned short* __restrict__ Wp, const float* __restrict__ bias,
    unsigned short* __restrict__ outb, unsigned char* __restrict__ outf8, int N)
{
    __shared__ unsigned short WL[8 * 4 * 128 * 8];   // 64 KB, full packed weights
    __shared__ unsigned short AL[64 * A_STRIDE];     // 5 KB, one 64x32 A chunk

    const int t = threadIdx.x;
    const int node0 = blockIdx.x * 64;
    const int w    = t >> 6;
    const int lane = t & 63;
    const int l15  = lane & 15;
    const int quad = lane >> 4;

#pragma unroll
    for (int i = 0; i < 16; ++i) {
        int slot = i * 256 + t;
        *(uint4*)&WL[slot * 8] = *(const uint4*)&Wp[slot * 8];
    }

    float bv[8];
#pragma unroll
    for (int nt = 0; nt < 8; ++nt) bv[nt] = bias[nt * 16 + l15];

    f32x4 acc[8];
#pragma unroll
    for (int nt = 0; nt < 8; ++nt) acc[nt] = (f32x4){0.f, 0.f, 0.f, 0.f};

    const int sr = t >> 2;        // 0..63
    const int sc = t & 3;         // 0..3
    const int srow = node0 + sr;

    for (int ks = 0; ks < 8; ++ks) {
        const unsigned short* Asrc = (ks < 4) ? aggb : xb;
        const int koff = (ks & 3) * 32;
        __syncthreads();
        uint4 av = make_uint4(0u, 0u, 0u, 0u);
        if (srow < N) av = *(const uint4*)&Asrc[(size_t)srow * C128 + koff + sc * 8];
        *(uint4*)&AL[sr * A_STRIDE + sc * 8] = av;
        __syncthreads();

        short8 a = *(const short8*)&AL[(w * 16 + l15) * A_STRIDE + quad * 8];
#pragma unroll
        for (int nt = 0; nt < 8; ++nt) {
            short8 b = *(const short8*)&WL[(((ks * 4 + quad) * 128) + nt * 16 + l15) * 8];
            acc[nt] = __builtin_amdgcn_mfma_f32_16x16x32_bf16(a, b, acc[nt], 0, 0, 0);
        }
    }

#pragma unroll
    for (int r = 0; r < 4; ++r) {
        int row = node0 + w * 16 + quad * 4 + r;
        if (row < N) {
#pragma unroll
            for (int nt = 0; nt < 8; ++nt) {
                float v = fmaxf(acc[nt][r] + bv[nt], 0.f);
                outb[(size_t)row * C128 + nt * 16 + l15] = f2bf(v);
                if (outf8) {
                    unsigned p8 = __builtin_amdgcn_cvt_pk_fp8_f32(v, 0.f, 0, false);
                    outf8[(size_t)row * C128 + nt * 16 + l15] = (unsigned char)(p8 & 0xff);
                }
            }
        }
    }
}

// ---------------- head: bf16 x3 @ W_lin + b_lin, log_softmax ----------------

__global__ __launch_bounds__(256) void head_kernel(
    const unsigned short* __restrict__ x, const float* __restrict__ Wl,
    const float* __restrict__ bl, float* __restrict__ out, int N)
{
    int n = blockIdx.x * blockDim.x + threadIdx.x;
    if (n >= N) return;
    float acc[OUT_CH];
#pragma unroll
    for (int c = 0; c < OUT_CH; ++c) acc[c] = bl[c];
    const ushort4* row = (const ushort4*)(x + (size_t)n * C128);
#pragma unroll 4
    for (int kk = 0; kk < 32; ++kk) {
        ushort4 u = row[kk];
        float vx = bf2f(u.x), vy = bf2f(u.y), vz = bf2f(u.z), vw = bf2f(u.w);
        int k = kk * 4;
#pragma unroll
        for (int c = 0; c < OUT_CH; ++c) {
            acc[c] += vx * Wl[(k + 0) * OUT_CH + c]
                    + vy * Wl[(k + 1) * OUT_CH + c]
                    + vz * Wl[(k + 2) * OUT_CH + c]
                    + vw * Wl[(k + 3) * OUT_CH + c];
        }
    }
    float m = acc[0];
#pragma unroll
    for (int c = 1; c < OUT_CH; ++c) m = fmaxf(m, acc[c]);
    float s = 0.f;
#pragma unroll
    for (int c = 0; c < OUT_CH; ++c) s += __expf(acc[c] - m);
    float lse = m + __logf(s);
#pragma unroll
    for (int c = 0; c < OUT_CH; ++c) out[(size_t)n * OUT_CH + c] = acc[c] - lse;
}

// ---------------- launch ----------------

extern "C" void kernel_launch(void* const* d_in, const int* in_sizes, int n_in,
                              void* d_out, int out_size, void* d_ws, size_t ws_size,
                              hipStream_t stream) {
    const float* x0   = (const float*)d_in[0];
    const int*   ei   = (const int*)  d_in[1];
    const float* ew   = (const float*)d_in[2];
    const float* W1r  = (const float*)d_in[3];
    const float* b1   = (const float*)d_in[4];
    const float* W1t  = (const float*)d_in[5];
    const float* W2r  = (const float*)d_in[6];
    const float* b2   = (const float*)d_in[7];
    const float* W2t  = (const float*)d_in[8];
    const float* W3r  = (const float*)d_in[9];
    const float* b3   = (const float*)d_in[10];
    const float* W3t  = (const float*)d_in[11];
    const float* Wlin = (const float*)d_in[12];
    const float* blin = (const float*)d_in[13];

    const int N = in_sizes[0] / C128;
    const int E = in_sizes[1] / 2;
    const int numTiles = (N + 255) / 256;

    char* ws = (char*)d_ws;
    size_t bb = (size_t)N * C128 * sizeof(unsigned short);   // 25.6 MB
    size_t fb = (size_t)N * C128;                            // 12.8 MB (fp8)
    unsigned short* aggb = (unsigned short*)(ws);
    unsigned short* xb0  = (unsigned short*)(ws + bb);
    unsigned short* xb1  = (unsigned short*)(ws + 2 * bb);
    unsigned char*  xf8  = (unsigned char*)(ws + 3 * bb);    // fp8 copy for gather
    unsigned short* Wp1  = (unsigned short*)(ws + 3 * bb + fb);
    unsigned short* Wp2  = Wp1 + 32768;
    unsigned short* Wp3  = Wp2 + 32768;
    int2*  csr     = (int2*)(Wp3 + 32768);
    int*   row_ptr = (int*)(csr + E);
    int*   cursor  = row_ptr + (N + 1);       // deg histogram, then fill cursor
    int*   tile_sums = cursor + N;
    int*   tile_off  = tile_sums + 512;

    const int edgeBlocks = (E + 255) / 256;

    // build CSR (dst-indexed), once per call
    hipMemsetAsync(cursor, 0, (size_t)N * sizeof(int), stream);
    hist_kernel<<<edgeBlocks * 8, 256, 0, stream>>>(ei, cursor, E);
    tile_sum_kernel<<<numTiles, 256, 0, stream>>>(cursor, tile_sums, N);
    tile_scan_kernel<<<1, 512, 0, stream>>>(tile_sums, tile_off, numTiles);
    scan_emit_kernel<<<numTiles, 256, 0, stream>>>(cursor, tile_off, row_ptr, N, E);
    fill_kernel<<<edgeBlocks * 8, 256, 0, stream>>>(ei, ew, cursor, csr, E);

    // bf16 + fp8 copies of layer-1 input, packed weights
    cvt_bf16_kernel<<<(N * C128 / 4 + 255) / 256, 256, 0, stream>>>(
        (const float4*)x0, (ushort4*)xb0, N * C128 / 4);
    cvt_fp8_kernel<<<(N * C128 / 4 + 255) / 256, 256, 0, stream>>>(
        (const float4*)x0, (unsigned*)xf8, N * C128 / 4);
    pack_w_kernel<<<128, 256, 0, stream>>>(W1r, W1t, Wp1);
    pack_w_kernel<<<128, 256, 0, stream>>>(W2r, W2t, Wp2);
    pack_w_kernel<<<128, 256, 0, stream>>>(W3r, W3t, Wp3);

    int gatherGrid = (N + 3) / 4;
    int gemmGrid   = (N + 63) / 64;

    // layer 1
    gather_fp8_kernel<<<gatherGrid, 256, 0, stream>>>(
        (const unsigned*)xf8, row_ptr, (const long long*)csr, aggb, N);
    gemm_mfma<<<gemmGrid, 256, 0, stream>>>(aggb, xb0, Wp1, b1, xb1, xf8, N);
    // layer 2
    gather_fp8_kernel<<<gatherGrid, 256, 0, stream>>>(
        (const unsigned*)xf8, row_ptr, (const long long*)csr, aggb, N);
    gemm_mfma<<<gemmGrid, 256, 0, stream>>>(aggb, xb1, Wp2, b2, xb0, xf8, N);
    // layer 3
    gather_fp8_kernel<<<gatherGrid, 256, 0, stream>>>(
        (const unsigned*)xf8, row_ptr, (const long long*)csr, aggb, N);
    gemm_mfma<<<gemmGrid, 256, 0, stream>>>(aggb, xb0, Wp3, b3, xb1, nullptr, N);
    // head
    head_kernel<<<(N + 255) / 256, 256, 0, stream>>>(xb1, Wlin, blin, (float*)d_out, N);
}